// Round 1
// 321.263 us; speedup vs baseline: 1.0514x; 1.0514x over previous
//
#include <hip/hip_runtime.h>
#include <hip/hip_bf16.h>

#define BATCH 32768
#define TSEQ 200

typedef __attribute__((ext_vector_type(8))) short short8;
typedef __attribute__((ext_vector_type(4))) float floatx4;
typedef __attribute__((ext_vector_type(2))) float f32x2;

#if __has_builtin(__builtin_amdgcn_exp2f)
__device__ __forceinline__ float EXP2(float x) { return __builtin_amdgcn_exp2f(x); }
#else
__device__ __forceinline__ float EXP2(float x) {
    float r; asm("v_exp_f32 %0, %1" : "=v"(r) : "v"(x)); return r;
}
#endif
__device__ __forceinline__ float RCP(float x) { return __builtin_amdgcn_rcpf(x); }

__device__ __forceinline__ float fast_sigmoid(float x) {
    return RCP(1.0f + EXP2(-1.4426950408889634f * x));
}
__device__ __forceinline__ float fast_tanh(float x) {
    float e = EXP2(2.8853900817779268f * x);
    return 1.0f - 2.0f * RCP(e + 1.0f);
}
__device__ __forceinline__ short f2bfs(float v) {
    __hip_bfloat16 h = __float2bfloat16(v);
    return __builtin_bit_cast(short, h);
}
__device__ __forceinline__ f32x2 splat2(float x) { f32x2 v; v[0] = x; v[1] = x; return v; }
__device__ __forceinline__ f32x2 pkfma(f32x2 a, f32x2 b, f32x2 c) {
    return __builtin_elementwise_fma(a, b, c);
}
template <int K>
__device__ __forceinline__ float qb(float v) {
    int i = __builtin_bit_cast(int, v);
    int r = __builtin_amdgcn_update_dpp(i, i, K * 0x55, 0xf, 0xf, false);
    return __builtin_bit_cast(float, r);
}
__device__ __forceinline__ void async16(void* lds, const void* g) {
    __builtin_amdgcn_global_load_lds(
        (const __attribute__((address_space(1))) unsigned int*)g,
        (__attribute__((address_space(3))) unsigned int*)lds, 16, 0, 0);
}

#define S_SIG (-1.4426950408889634f)   // sigmoid rows: 2^(S_SIG*g) = e^-g
#define S_TANH (2.8853900817779268f)   // tanh rows:    2^(S_TANH*g) = e^(2g)

// ---------------- workspace layout (bytes) ----------------
// hh k-index: k' = (t>>2)*16 + q*4 + (t&3)  — quad-contiguous 32B stores
#define WS_HH  0                         // bf16 [2][B][800]
#define WS_WHB 104857600                 // bf16 [128][800] cols permuted to k'
#define WS_WLB (WS_WHB + 204800)
#define WS_W1B (WS_WLB + 204800)         // bf16 [80][256]
#define WS_W2B (WS_W1B + 40960)          // bf16 [48][96] zero-pad
#define WS_U   (WS_W2B + 9216)           // f32 [401]

struct LW { const float* p[16]; };

// ---------------- kernel 0: weight prep / folds ----------------
__global__ __launch_bounds__(256) void k_prep(
    const float* __restrict__ WH, const float* __restrict__ WL,
    const float* __restrict__ W1, const float* __restrict__ W2,
    const float* __restrict__ W3, const float* __restrict__ Wp,
    const float* __restrict__ bp, const float* __restrict__ b3,
    __hip_bfloat16* __restrict__ WHbf, __hip_bfloat16* __restrict__ WLbf,
    __hip_bfloat16* __restrict__ W1bf, __hip_bfloat16* __restrict__ W2bf,
    float* __restrict__ u)
{
    int gid = blockIdx.x * 256 + threadIdx.x;   // 400 blocks = 102400 = 128*800
    int n = gid / 800, k = gid - n * 800;
    int t = k >> 2, q = k & 3;
    int kp = (t >> 2) * 16 + q * 4 + (t & 3);
    int dst = n * 800 + kp;
    WHbf[dst] = __float2bfloat16(WH[gid]);
    WLbf[dst] = __float2bfloat16(WL[gid]);
    if (gid < 20480) W1bf[gid] = __float2bfloat16(W1[gid]);
    if (gid < 4608) {
        int rr = gid / 96, cc = gid - rr * 96;
        float v = (rr < 40 && cc < 80) ? W2[rr * 80 + cc] : 0.0f;
        W2bf[gid] = __float2bfloat16(v);
    }
    if (gid < 400) {
        float a = 0.f;
        for (int j = 0; j < 40; ++j) a = fmaf(W3[40 + j], Wp[j * 400 + gid], a);
        u[gid] = a;
    } else if (gid == 400) {
        float a = b3[0];
        for (int j = 0; j < 40; ++j) a = fmaf(W3[40 + j], bp[j], a);
        u[400] = a;
    }
}

// ---------------- kernel 1: fused LSTM + GEMM + MLP tail ----------------
// Block = 32 samples x both rnns (64 groups of 4 lanes). LSTM core loop is
// byte-identical to the previous k_lstm. Epilogue: each wave owns (f, mtile)
// and reads back exactly the hh rows its own lanes wrote (L2-warm), runs
// z = tanh(hh @ W.T + b) with double-buffered 16KB B-staging, then z1/z2/out
// fully in LDS. LDS total 33KB -> 4 blocks/CU preserved for the LSTM phase.
__global__ __launch_bounds__(256)
__attribute__((amdgpu_waves_per_eu(4, 4))) void k_fused(
    const float* __restrict__ x, LW w, const float* __restrict__ u,
    __hip_bfloat16* __restrict__ hh,
    const __hip_bfloat16* __restrict__ WHbf, const __hip_bfloat16* __restrict__ WLbf,
    const float* __restrict__ bH, const float* __restrict__ bL,
    const __hip_bfloat16* __restrict__ W1bf, const __hip_bfloat16* __restrict__ W2bf,
    const float* __restrict__ b1, const float* __restrict__ b2,
    const float* __restrict__ W3, float* __restrict__ out)
{
    // 0..32767:  Bs [2][256][32] bf16 staging; aliased after GEMM by:
    //   zl  [32][264] bf16 @ 0      (16896 B)
    //   z1l [32][104] bf16 @ 17024  (6656 B)
    //   z2l [32][44]  f32  @ 23808  (5632 B)
    // 32768..33023: ot [64] f32
    __shared__ __align__(16) char smem[33024];
    short* Bse = (short*)smem;
    short* zl  = (short*)smem;
    short* z1l = (short*)(smem + 17024);
    float* z2l = (float*)(smem + 23808);
    float* ot  = (float*)(smem + 32768);

    int tid = threadIdx.x;
    int q = tid & 3;
    int g = tid >> 2;                    // 0..63: group in block
    int r = tid >> 7;                    // wave-uniform rnn index
    int b = blockIdx.x * 32 + (g & 31);

    const float* Wih0 = w.p[r * 8 + 0];
    const float* Whh0 = w.p[r * 8 + 1];
    const float* bih0 = w.p[r * 8 + 2];
    const float* bhh0 = w.p[r * 8 + 3];
    const float* Wih1 = w.p[r * 8 + 4];
    const float* Whh1 = w.p[r * 8 + 5];
    const float* bih1 = w.p[r * 8 + 6];
    const float* bhh1 = w.p[r * 8 + 7];

    // pairs: p=0 -> (i,f) [sigmoid], p=1 -> (g,o) [tanh, sigmoid]
    f32x2 wx0p[2], bb0p[2], bb1p[2], whh0p[2][4], wih1p[2][4], whh1p[2][4];
#pragma unroll
    for (int p = 0; p < 2; ++p) {
#pragma unroll
        for (int c = 0; c < 2; ++c) {
            int G = 2 * p + c;
            int j = 4 * G + q;
            float sc = (G == 2) ? S_TANH : S_SIG;
            wx0p[p][c] = Wih0[j] * sc;
            bb0p[p][c] = (bih0[j] + bhh0[j]) * sc;
            bb1p[p][c] = (bih1[j] + bhh1[j]) * sc;
#pragma unroll
            for (int k = 0; k < 4; ++k) {
                whh0p[p][k][c] = Whh0[j * 4 + k] * sc;
                wih1p[p][k][c] = Wih1[j * 4 + k] * sc;
                whh1p[p][k][c] = Whh1[j * 4 + k] * sc;
            }
        }
    }

    const float* xp = x + ((size_t)b * 2 + r) * TSEQ;
    const float* up = u + r * TSEQ;
    __hip_bfloat16* hp = hh + ((size_t)r * BATCH + b) * 800 + q * 4;

    float h0 = 0.f, c0 = 0.f, h1 = 0.f, c1 = 0.f, accO = 0.f;

    for (int tb = 0; tb < TSEQ; tb += 4) {
        float4 xv = *(const float4*)(xp + tb);
        float4 uv = *(const float4*)(up + tb);
        float xa[4] = {xv.x, xv.y, xv.z, xv.w};
        float ua[4] = {uv.x, uv.y, uv.z, uv.w};
        float hb[4];
#pragma unroll
        for (int j = 0; j < 4; ++j) {
            float xt = xa[j];
            accO = fmaf(xt, ua[j], accO);

            // ---- layer 0 ----
            float a0 = qb<0>(h0), a1 = qb<1>(h0), a2 = qb<2>(h0), a3 = qb<3>(h0);
            f32x2 g0 = pkfma(splat2(xt), wx0p[0], bb0p[0]);
            f32x2 g1 = pkfma(splat2(xt), wx0p[1], bb0p[1]);
            g0 = pkfma(whh0p[0][0], splat2(a0), g0); g1 = pkfma(whh0p[1][0], splat2(a0), g1);
            g0 = pkfma(whh0p[0][1], splat2(a1), g0); g1 = pkfma(whh0p[1][1], splat2(a1), g1);
            g0 = pkfma(whh0p[0][2], splat2(a2), g0); g1 = pkfma(whh0p[1][2], splat2(a2), g1);
            g0 = pkfma(whh0p[0][3], splat2(a3), g0); g1 = pkfma(whh0p[1][3], splat2(a3), g1);
            float ig = RCP(1.0f + EXP2(g0[0]));          // e^-g pre-scaled
            float fg = RCP(1.0f + EXP2(g0[1]));
            float og = RCP(1.0f + EXP2(g1[1]));
            float tg = 1.0f - 2.0f * RCP(EXP2(g1[0]) + 1.0f);   // tanh, e^2g pre-scaled
            c0 = fmaf(fg, c0, ig * tg);
            float th0 = 1.0f - 2.0f * RCP(EXP2(S_TANH * c0) + 1.0f);
            h0 = og * th0;

            // ---- layer 1 ----
            float p0 = qb<0>(h0), p1 = qb<1>(h0), p2 = qb<2>(h0), p3 = qb<3>(h0);
            float q0 = qb<0>(h1), q1 = qb<1>(h1), q2 = qb<2>(h1), q3 = qb<3>(h1);
            g0 = bb1p[0]; g1 = bb1p[1];
            g0 = pkfma(wih1p[0][0], splat2(p0), g0); g1 = pkfma(wih1p[1][0], splat2(p0), g1);
            g0 = pkfma(wih1p[0][1], splat2(p1), g0); g1 = pkfma(wih1p[1][1], splat2(p1), g1);
            g0 = pkfma(wih1p[0][2], splat2(p2), g0); g1 = pkfma(wih1p[1][2], splat2(p2), g1);
            g0 = pkfma(wih1p[0][3], splat2(p3), g0); g1 = pkfma(wih1p[1][3], splat2(p3), g1);
            g0 = pkfma(whh1p[0][0], splat2(q0), g0); g1 = pkfma(whh1p[1][0], splat2(q0), g1);
            g0 = pkfma(whh1p[0][1], splat2(q1), g0); g1 = pkfma(whh1p[1][1], splat2(q1), g1);
            g0 = pkfma(whh1p[0][2], splat2(q2), g0); g1 = pkfma(whh1p[1][2], splat2(q2), g1);
            g0 = pkfma(whh1p[0][3], splat2(q3), g0); g1 = pkfma(whh1p[1][3], splat2(q3), g1);
            ig = RCP(1.0f + EXP2(g0[0]));
            fg = RCP(1.0f + EXP2(g0[1]));
            og = RCP(1.0f + EXP2(g1[1]));
            tg = 1.0f - 2.0f * RCP(EXP2(g1[0]) + 1.0f);
            c1 = fmaf(fg, c1, ig * tg);
            float th1 = 1.0f - 2.0f * RCP(EXP2(S_TANH * c1) + 1.0f);
            h1 = og * th1;
            hb[j] = h1;
        }
        ushort4 pk;
        pk.x = (unsigned short)f2bfs(hb[0]);
        pk.y = (unsigned short)f2bfs(hb[1]);
        pk.z = (unsigned short)f2bfs(hb[2]);
        pk.w = (unsigned short)f2bfs(hb[3]);
        *(ushort4*)(hp + tb * 4) = pk;   // k' = tb*4 + q*4 + 0..3; quad = 32B contig
    }
    if (q == 0) ot[g] = accO;
    __syncthreads();   // drains hh stores (vmcnt 0 before barrier) + ot visible

    // ---- epilogue: z = tanh(hh @ W.T + b) for this block's 32 samples ----
    int wv = tid >> 6, lane = tid & 63, l15 = lane & 15, quad = lane >> 4;
    int b0 = blockIdx.x * 32;
    int f = wv >> 1, mt = wv & 1;        // wave -> (gemm half, 16-row tile)

    // B staging: 256 rows = [WH(128); WL(128)] x 32 k'-cols per chunk (16 KB)
    const __hip_bfloat16* gB0 = WHbf + (size_t)(tid >> 2) * 800 + (tid & 3) * 8;
    const __hip_bfloat16* gB2 = WLbf + (size_t)(tid >> 2) * 800 + (tid & 3) * 8;
    // each wave reads back the hh rows its own lanes produced (L2-warm)
    const __hip_bfloat16* Ab =
        hh + ((size_t)f * BATCH + b0 + mt * 16 + l15) * 800 + quad * 8;

#define PF(kc, buf)                                                    \
    do {                                                               \
        char* lb_ = smem + (buf) * 16384 + wv * 1024;                  \
        async16(lb_,          gB0 + (kc) * 32);                        \
        async16(lb_ + 4096,   gB0 + 64 * 800 + (kc) * 32);             \
        async16(lb_ + 8192,   gB2 + (kc) * 32);                        \
        async16(lb_ + 12288,  gB2 + 64 * 800 + (kc) * 32);             \
    } while (0)

    floatx4 acc[8] = {};
    short8 af = *(const short8*)(const void*)Ab;
    PF(0, 0);
    for (int kc = 0; kc < 25; ++kc) {
        __syncthreads();
        short8 afn = af;
        if (kc < 24) {
            PF(kc + 1, (kc + 1) & 1);
            afn = *(const short8*)(const void*)(Ab + (kc + 1) * 32);
        }
        const short* Bb = Bse + (kc & 1) * 8192 + f * 4096;
#pragma unroll
        for (int nt = 0; nt < 8; ++nt) {
            short8 bfr = *(const short8*)(const void*)(Bb + (nt * 16 + l15) * 32 + quad * 8);
            acc[nt] = __builtin_amdgcn_mfma_f32_16x16x32_bf16(af, bfr, acc[nt], 0, 0, 0);
        }
        af = afn;
    }
#undef PF
    __syncthreads();   // Bs dead from here; write z into aliased region

    {
        const float* bias = f ? bL : bH;
#pragma unroll
        for (int nt = 0; nt < 8; ++nt) {
            float bb = bias[nt * 16 + l15];
            int c = f * 128 + nt * 16 + l15;
#pragma unroll
            for (int rg = 0; rg < 4; ++rg) {
                int m = mt * 16 + quad * 4 + rg;
                zl[m * 264 + c] = f2bfs(fast_tanh(acc[nt][rg] + bb));
            }
        }
    }
    __syncthreads();

    // ---- z1 = tanh(z @ W1.T + b1): M=32 K=256 N=80 (waves 0-1) ----
    if (wv < 2) {
        floatx4 a1[5] = {};
        for (int kc = 0; kc < 8; ++kc) {
            short8 afz = *(const short8*)(const void*)
                &zl[(wv * 16 + l15) * 264 + kc * 32 + quad * 8];
#pragma unroll
            for (int nt = 0; nt < 5; ++nt) {
                short8 bfr = *(const short8*)(const void*)
                    (W1bf + (size_t)(nt * 16 + l15) * 256 + kc * 32 + quad * 8);
                a1[nt] = __builtin_amdgcn_mfma_f32_16x16x32_bf16(afz, bfr, a1[nt], 0, 0, 0);
            }
        }
#pragma unroll
        for (int nt = 0; nt < 5; ++nt) {
            int n = nt * 16 + l15;
            float bb = b1[n];
#pragma unroll
            for (int rg = 0; rg < 4; ++rg)
                z1l[(wv * 16 + quad * 4 + rg) * 104 + n] = f2bfs(fast_tanh(a1[nt][rg] + bb));
        }
    } else {
        // zero-pad z1 cols 80..95 (K-pad for z2's 96-wide contraction)
        int i0 = tid - 128;
        for (int i = i0; i < 512; i += 128) {
            int rr = i >> 4, cc = 80 + (i & 15);
            z1l[rr * 104 + cc] = 0;
        }
    }
    __syncthreads();

    // ---- z2 = tanh(z1 @ W2.T + b2): M=32 K=96 N=48(keep 40) (waves 0-1) ----
    if (wv < 2) {
        floatx4 a2[3] = {};
        for (int kc = 0; kc < 3; ++kc) {
            short8 afz = *(const short8*)(const void*)
                &z1l[(wv * 16 + l15) * 104 + kc * 32 + quad * 8];
#pragma unroll
            for (int nt = 0; nt < 3; ++nt) {
                short8 bfr = *(const short8*)(const void*)
                    (W2bf + (size_t)(nt * 16 + l15) * 96 + kc * 32 + quad * 8);
                a2[nt] = __builtin_amdgcn_mfma_f32_16x16x32_bf16(afz, bfr, a2[nt], 0, 0, 0);
            }
        }
#pragma unroll
        for (int nt = 0; nt < 3; ++nt) {
            int n = nt * 16 + l15;
            if (n < 40) {
                float bb = b2[n];
#pragma unroll
                for (int rg = 0; rg < 4; ++rg)
                    z2l[(wv * 16 + quad * 4 + rg) * 44 + n] = fast_tanh(a2[nt][rg] + bb);
            }
        }
    }
    __syncthreads();

    // ---- final: out = sigmoid([z2, other] . W3 + b3) ----
    if (tid < 32) {
        float s = u[400] + ot[tid] + ot[32 + tid];
        for (int j = 0; j < 40; ++j) s = fmaf(z2l[tid * 44 + j], W3[j], s);
        out[b0 + tid] = fast_sigmoid(s);
    }
}

extern "C" void kernel_launch(void* const* d_in, const int* in_sizes, int n_in,
                              void* d_out, int out_size, void* d_ws, size_t ws_size,
                              hipStream_t stream)
{
    const float* x = (const float*)d_in[0];
    LW w;
    for (int i = 0; i < 16; ++i) w.p[i] = (const float*)d_in[1 + i];
    const float* Wp = (const float*)d_in[17];
    const float* bp = (const float*)d_in[18];
    const float* WH = (const float*)d_in[19];
    const float* bH = (const float*)d_in[20];
    const float* WL = (const float*)d_in[21];
    const float* bL = (const float*)d_in[22];
    const float* W1 = (const float*)d_in[23];
    const float* b1 = (const float*)d_in[24];
    const float* W2 = (const float*)d_in[25];
    const float* b2 = (const float*)d_in[26];
    const float* W3 = (const float*)d_in[27];
    const float* b3 = (const float*)d_in[28];

    char* ws = (char*)d_ws;
    __hip_bfloat16* hh   = (__hip_bfloat16*)(ws + WS_HH);
    __hip_bfloat16* WHbf = (__hip_bfloat16*)(ws + WS_WHB);
    __hip_bfloat16* WLbf = (__hip_bfloat16*)(ws + WS_WLB);
    __hip_bfloat16* W1bf = (__hip_bfloat16*)(ws + WS_W1B);
    __hip_bfloat16* W2bf = (__hip_bfloat16*)(ws + WS_W2B);
    float* u = (float*)(ws + WS_U);
    float* out = (float*)d_out;

    k_prep<<<400, 256, 0, stream>>>(WH, WL, W1, W2, W3, Wp, bp, b3,
                                    WHbf, WLbf, W1bf, W2bf, u);
    k_fused<<<1024, 256, 0, stream>>>(x, w, u, hh, WHbf, WLbf, bH, bL,
                                      W1bf, W2bf, b1, b2, W3, out);
}

// Round 3
// 318.000 us; speedup vs baseline: 1.0622x; 1.0103x over previous
//
#include <hip/hip_runtime.h>
#include <hip/hip_bf16.h>

#define BATCH 32768
#define TSEQ 200

typedef __attribute__((ext_vector_type(8))) short short8;
typedef __attribute__((ext_vector_type(4))) float floatx4;
typedef __attribute__((ext_vector_type(2))) float f32x2;

#if __has_builtin(__builtin_amdgcn_exp2f)
__device__ __forceinline__ float EXP2(float x) { return __builtin_amdgcn_exp2f(x); }
#else
__device__ __forceinline__ float EXP2(float x) {
    float r; asm("v_exp_f32 %0, %1" : "=v"(r) : "v"(x)); return r;
}
#endif
__device__ __forceinline__ float RCP(float x) { return __builtin_amdgcn_rcpf(x); }

__device__ __forceinline__ float fast_sigmoid(float x) {
    return RCP(1.0f + EXP2(-1.4426950408889634f * x));
}
__device__ __forceinline__ float fast_tanh(float x) {
    float e = EXP2(2.8853900817779268f * x);
    return 1.0f - 2.0f * RCP(e + 1.0f);
}
__device__ __forceinline__ short f2bfs(float v) {
    __hip_bfloat16 h = __float2bfloat16(v);
    return __builtin_bit_cast(short, h);
}
__device__ __forceinline__ f32x2 splat2(float x) { f32x2 v; v[0] = x; v[1] = x; return v; }
__device__ __forceinline__ f32x2 pkfma(f32x2 a, f32x2 b, f32x2 c) {
    return __builtin_elementwise_fma(a, b, c);
}
// Opaque register pin: forces the scaled-weight pairs to stay resident in
// VGPRs across the 200-step loop (R1 post-mortem: VGPR_Count=56 << the ~85
// needed -> compiler was rematerializing/reloading weights inside the loop).
__device__ __forceinline__ void keepv(f32x2& v) {
    float a = v[0], b = v[1];
    asm volatile("" : "+v"(a), "+v"(b));
    v[0] = a; v[1] = b;
}
template <int K>
__device__ __forceinline__ float qb(float v) {
    int i = __builtin_bit_cast(int, v);
    int r = __builtin_amdgcn_update_dpp(i, i, K * 0x55, 0xf, 0xf, false);
    return __builtin_bit_cast(float, r);
}
__device__ __forceinline__ void async16(void* lds, const void* g) {
    __builtin_amdgcn_global_load_lds(
        (const __attribute__((address_space(1))) unsigned int*)g,
        (__attribute__((address_space(3))) unsigned int*)lds, 16, 0, 0);
}

#define S_SIG (-1.4426950408889634f)   // sigmoid rows: 2^(S_SIG*g) = e^-g
#define S_TANH (2.8853900817779268f)   // tanh rows:    2^(S_TANH*g) = e^(2g)

// ---------------- workspace layout (bytes) ----------------
// hh k-index: k' = (t>>2)*16 + q*4 + (t&3)  — quad-contiguous 32B stores
#define WS_HH  0                         // bf16 [2][B][800]
#define WS_WHB 104857600                 // bf16 [128][800] cols permuted to k'
#define WS_WLB (WS_WHB + 204800)
#define WS_W1B (WS_WLB + 204800)         // bf16 [80][256]
#define WS_W2B (WS_W1B + 40960)          // bf16 [48][96] zero-pad
#define WS_U   (WS_W2B + 9216)           // f32 [401]

struct LW { const float* p[16]; };

// ---------------- kernel 0: weight prep / folds ----------------
__global__ __launch_bounds__(256) void k_prep(
    const float* __restrict__ WH, const float* __restrict__ WL,
    const float* __restrict__ W1, const float* __restrict__ W2,
    const float* __restrict__ W3, const float* __restrict__ Wp,
    const float* __restrict__ bp, const float* __restrict__ b3,
    __hip_bfloat16* __restrict__ WHbf, __hip_bfloat16* __restrict__ WLbf,
    __hip_bfloat16* __restrict__ W1bf, __hip_bfloat16* __restrict__ W2bf,
    float* __restrict__ u)
{
    int gid = blockIdx.x * 256 + threadIdx.x;   // 400 blocks = 102400 = 128*800
    int n = gid / 800, k = gid - n * 800;
    int t = k >> 2, q = k & 3;
    int kp = (t >> 2) * 16 + q * 4 + (t & 3);
    int dst = n * 800 + kp;
    WHbf[dst] = __float2bfloat16(WH[gid]);
    WLbf[dst] = __float2bfloat16(WL[gid]);
    if (gid < 20480) W1bf[gid] = __float2bfloat16(W1[gid]);
    if (gid < 4608) {
        int rr = gid / 96, cc = gid - rr * 96;
        float v = (rr < 40 && cc < 80) ? W2[rr * 80 + cc] : 0.0f;
        W2bf[gid] = __float2bfloat16(v);
    }
    if (gid < 400) {
        float a = 0.f;
        for (int j = 0; j < 40; ++j) a = fmaf(W3[40 + j], Wp[j * 400 + gid], a);
        u[gid] = a;
    } else if (gid == 400) {
        float a = b3[0];
        for (int j = 0; j < 40; ++j) a = fmaf(W3[40 + j], bp[j], a);
        u[400] = a;
    }
}

// ---------------- kernel 1: fused LSTM + GEMM + MLP tail ----------------
// Block = 32 samples x both rnns (64 groups of 4 lanes). Epilogue: each wave
// owns (f, mtile), reads back its own hh rows (L2-warm), z = tanh(hh@W.T+b)
// with double-buffered transpose-staged B (conflict-free reads), then
// z1/z2/out fully in LDS.
__global__ __launch_bounds__(256)
__attribute__((amdgpu_waves_per_eu(4, 4))) void k_fused(
    const float* __restrict__ x, LW w, const float* __restrict__ u,
    __hip_bfloat16* __restrict__ hh,
    const __hip_bfloat16* __restrict__ WHbf, const __hip_bfloat16* __restrict__ WLbf,
    const float* __restrict__ bH, const float* __restrict__ bL,
    const __hip_bfloat16* __restrict__ W1bf, const __hip_bfloat16* __restrict__ W2bf,
    const float* __restrict__ b1, const float* __restrict__ b2,
    const float* __restrict__ W3, float* __restrict__ out)
{
    // 0..32767:  Bs [2][256][32] bf16 staging; aliased after GEMM by:
    //   zl  [32][264] bf16 @ 0      (16896 B)
    //   z1l [32][104] bf16 @ 17024  (6656 B)
    //   z2l [32][44]  f32  @ 23808  (5632 B)
    // 32768..33023: ot [64] f32
    __shared__ __align__(16) char smem[33024];
    short* Bse = (short*)smem;
    short* zl  = (short*)smem;
    short* z1l = (short*)(smem + 17024);
    float* z2l = (float*)(smem + 23808);
    float* ot  = (float*)(smem + 32768);

    int tid = threadIdx.x;
    int q = tid & 3;
    int g = tid >> 2;                    // 0..63: group in block
    int r = tid >> 7;                    // wave-uniform rnn index
    int b = blockIdx.x * 32 + (g & 31);

    const float* Wih0 = w.p[r * 8 + 0];
    const float* Whh0 = w.p[r * 8 + 1];
    const float* bih0 = w.p[r * 8 + 2];
    const float* bhh0 = w.p[r * 8 + 3];
    const float* Wih1 = w.p[r * 8 + 4];
    const float* Whh1 = w.p[r * 8 + 5];
    const float* bih1 = w.p[r * 8 + 6];
    const float* bhh1 = w.p[r * 8 + 7];

    // pairs: p=0 -> (i,f) [sigmoid], p=1 -> (g,o) [tanh, sigmoid]
    f32x2 wx0p[2], bb0p[2], bb1p[2], whh0p[2][4], wih1p[2][4], whh1p[2][4];
#pragma unroll
    for (int p = 0; p < 2; ++p) {
#pragma unroll
        for (int c = 0; c < 2; ++c) {
            int G = 2 * p + c;
            int j = 4 * G + q;
            float sc = (G == 2) ? S_TANH : S_SIG;
            wx0p[p][c] = Wih0[j] * sc;
            bb0p[p][c] = (bih0[j] + bhh0[j]) * sc;
            bb1p[p][c] = (bih1[j] + bhh1[j]) * sc;
#pragma unroll
            for (int k = 0; k < 4; ++k) {
                whh0p[p][k][c] = Whh0[j * 4 + k] * sc;
                wih1p[p][k][c] = Wih1[j * 4 + k] * sc;
                whh1p[p][k][c] = Whh1[j * 4 + k] * sc;
            }
        }
    }
    // pin all 30 scaled pairs in VGPRs for the whole loop
#pragma unroll
    for (int p = 0; p < 2; ++p) {
        keepv(wx0p[p]); keepv(bb0p[p]); keepv(bb1p[p]);
#pragma unroll
        for (int k = 0; k < 4; ++k) {
            keepv(whh0p[p][k]); keepv(wih1p[p][k]); keepv(whh1p[p][k]);
        }
    }

    const float* xp = x + ((size_t)b * 2 + r) * TSEQ;
    const float* up = u + r * TSEQ;
    __hip_bfloat16* hp = hh + ((size_t)r * BATCH + b) * 800 + q * 4;

    float h0 = 0.f, c0 = 0.f, h1 = 0.f, c1 = 0.f, accO = 0.f;

    for (int tb = 0; tb < TSEQ; tb += 4) {
        float4 xv = *(const float4*)(xp + tb);
        float4 uv = *(const float4*)(up + tb);
        float xa[4] = {xv.x, xv.y, xv.z, xv.w};
        float ua[4] = {uv.x, uv.y, uv.z, uv.w};
        float hb[4];
#pragma unroll
        for (int j = 0; j < 4; ++j) {
            float xt = xa[j];
            accO = fmaf(xt, ua[j], accO);

            // ---- layer 0 ----
            float a0 = qb<0>(h0), a1 = qb<1>(h0), a2 = qb<2>(h0), a3 = qb<3>(h0);
            f32x2 g0 = pkfma(splat2(xt), wx0p[0], bb0p[0]);
            f32x2 g1 = pkfma(splat2(xt), wx0p[1], bb0p[1]);
            g0 = pkfma(whh0p[0][0], splat2(a0), g0); g1 = pkfma(whh0p[1][0], splat2(a0), g1);
            g0 = pkfma(whh0p[0][1], splat2(a1), g0); g1 = pkfma(whh0p[1][1], splat2(a1), g1);
            g0 = pkfma(whh0p[0][2], splat2(a2), g0); g1 = pkfma(whh0p[1][2], splat2(a2), g1);
            g0 = pkfma(whh0p[0][3], splat2(a3), g0); g1 = pkfma(whh0p[1][3], splat2(a3), g1);
            float ig = RCP(1.0f + EXP2(g0[0]));          // e^-g pre-scaled
            float fg = RCP(1.0f + EXP2(g0[1]));
            float og = RCP(1.0f + EXP2(g1[1]));
            float tg = 1.0f - 2.0f * RCP(EXP2(g1[0]) + 1.0f);   // tanh, e^2g pre-scaled
            c0 = fmaf(fg, c0, ig * tg);
            float th0 = 1.0f - 2.0f * RCP(EXP2(S_TANH * c0) + 1.0f);
            h0 = og * th0;

            // ---- layer 1 ----
            float p0 = qb<0>(h0), p1 = qb<1>(h0), p2 = qb<2>(h0), p3 = qb<3>(h0);
            float q0 = qb<0>(h1), q1 = qb<1>(h1), q2 = qb<2>(h1), q3 = qb<3>(h1);
            g0 = bb1p[0]; g1 = bb1p[1];
            g0 = pkfma(wih1p[0][0], splat2(p0), g0); g1 = pkfma(wih1p[1][0], splat2(p0), g1);
            g0 = pkfma(wih1p[0][1], splat2(p1), g0); g1 = pkfma(wih1p[1][1], splat2(p1), g1);
            g0 = pkfma(wih1p[0][2], splat2(p2), g0); g1 = pkfma(wih1p[1][2], splat2(p2), g1);
            g0 = pkfma(wih1p[0][3], splat2(p3), g0); g1 = pkfma(wih1p[1][3], splat2(p3), g1);
            g0 = pkfma(whh1p[0][0], splat2(q0), g0); g1 = pkfma(whh1p[1][0], splat2(q0), g1);
            g0 = pkfma(whh1p[0][1], splat2(q1), g0); g1 = pkfma(whh1p[1][1], splat2(q1), g1);
            g0 = pkfma(whh1p[0][2], splat2(q2), g0); g1 = pkfma(whh1p[1][2], splat2(q2), g1);
            g0 = pkfma(whh1p[0][3], splat2(q3), g0); g1 = pkfma(whh1p[1][3], splat2(q3), g1);
            ig = RCP(1.0f + EXP2(g0[0]));
            fg = RCP(1.0f + EXP2(g0[1]));
            og = RCP(1.0f + EXP2(g1[1]));
            tg = 1.0f - 2.0f * RCP(EXP2(g1[0]) + 1.0f);
            c1 = fmaf(fg, c1, ig * tg);
            float th1 = 1.0f - 2.0f * RCP(EXP2(S_TANH * c1) + 1.0f);
            h1 = og * th1;
            hb[j] = h1;
        }
        ushort4 pk;
        pk.x = (unsigned short)f2bfs(hb[0]);
        pk.y = (unsigned short)f2bfs(hb[1]);
        pk.z = (unsigned short)f2bfs(hb[2]);
        pk.w = (unsigned short)f2bfs(hb[3]);
        *(ushort4*)(hp + tb * 4) = pk;   // k' = tb*4 + q*4 + 0..3; quad = 32B contig
    }
    if (q == 0) ot[g] = accO;
    __syncthreads();   // drains hh stores + ot visible

    // ---- epilogue: z = tanh(hh @ W.T + b) for this block's 32 samples ----
    int wv = tid >> 6, lane = tid & 63, l15 = lane & 15, quad = lane >> 4;
    int b0 = blockIdx.x * 32;
    int f = wv >> 1, mt = wv & 1;        // wave -> (gemm half, 16-row tile)

    // B staging, TRANSPOSED chunks (R2 audit: 64B-row layout is an inherent
    // 8-way conflict; no slot-XOR fixes it). Each 1KB chunk = 16-row x 64B
    // W-tile; lane l fetches global row (l&15), 16B-col (l>>4), so the MFMA
    // B-read becomes identity lane->lane*16B: consecutive banks, 0 conflicts.
    const __hip_bfloat16* gB0 = WHbf + (size_t)(wv * 16 + (tid & 15)) * 800 + ((tid >> 4) & 3) * 8;
    const __hip_bfloat16* gB2 = WLbf + (size_t)(wv * 16 + (tid & 15)) * 800 + ((tid >> 4) & 3) * 8;
    // each wave reads back the hh rows its own lanes produced (L2-warm)
    const __hip_bfloat16* Ab =
        hh + ((size_t)f * BATCH + b0 + mt * 16 + l15) * 800 + quad * 8;

#define PF(kc, buf)                                                    \
    do {                                                               \
        char* lb_ = smem + (buf) * 16384 + wv * 1024;                  \
        async16(lb_,          gB0 + (kc) * 32);                        \
        async16(lb_ + 4096,   gB0 + 64 * 800 + (kc) * 32);             \
        async16(lb_ + 8192,   gB2 + (kc) * 32);                        \
        async16(lb_ + 12288,  gB2 + 64 * 800 + (kc) * 32);             \
    } while (0)

    floatx4 acc[8] = {};
    short8 af = *(const short8*)(const void*)Ab;
    PF(0, 0);
    for (int kc = 0; kc < 25; ++kc) {
        __syncthreads();
        short8 afn = af;
        if (kc < 24) {
            PF(kc + 1, (kc + 1) & 1);
            afn = *(const short8*)(const void*)(Ab + (kc + 1) * 32);
        }
        // chunk nt of [WH;WL] half f, identity slot = lane
        const short* Bb = Bse + (kc & 1) * 8192 + f * 4096 + lane * 8;
#pragma unroll
        for (int nt = 0; nt < 8; ++nt) {
            short8 bfr = *(const short8*)(const void*)(Bb + nt * 512);
            acc[nt] = __builtin_amdgcn_mfma_f32_16x16x32_bf16(af, bfr, acc[nt], 0, 0, 0);
        }
        af = afn;
    }
#undef PF
    __syncthreads();   // Bs dead from here; write z into aliased region

    {
        const float* bias = f ? bL : bH;
#pragma unroll
        for (int nt = 0; nt < 8; ++nt) {
            float bb = bias[nt * 16 + l15];
            int c = f * 128 + nt * 16 + l15;
#pragma unroll
            for (int rg = 0; rg < 4; ++rg) {
                int m = mt * 16 + quad * 4 + rg;
                zl[m * 264 + c] = f2bfs(fast_tanh(acc[nt][rg] + bb));
            }
        }
    }
    __syncthreads();

    // ---- z1 = tanh(z @ W1.T + b1): M=32 K=256 N=80 (waves 0-1) ----
    if (wv < 2) {
        floatx4 a1[5] = {};
        for (int kc = 0; kc < 8; ++kc) {
            short8 afz = *(const short8*)(const void*)
                &zl[(wv * 16 + l15) * 264 + kc * 32 + quad * 8];
#pragma unroll
            for (int nt = 0; nt < 5; ++nt) {
                short8 bfr = *(const short8*)(const void*)
                    (W1bf + (size_t)(nt * 16 + l15) * 256 + kc * 32 + quad * 8);
                a1[nt] = __builtin_amdgcn_mfma_f32_16x16x32_bf16(afz, bfr, a1[nt], 0, 0, 0);
            }
        }
#pragma unroll
        for (int nt = 0; nt < 5; ++nt) {
            int n = nt * 16 + l15;
            float bb = b1[n];
#pragma unroll
            for (int rg = 0; rg < 4; ++rg)
                z1l[(wv * 16 + quad * 4 + rg) * 104 + n] = f2bfs(fast_tanh(a1[nt][rg] + bb));
        }
    } else {
        // zero-pad z1 cols 80..95 (K-pad for z2's 96-wide contraction)
        int i0 = tid - 128;
        for (int i = i0; i < 512; i += 128) {
            int rr = i >> 4, cc = 80 + (i & 15);
            z1l[rr * 104 + cc] = 0;
        }
    }
    __syncthreads();

    // ---- z2 = tanh(z1 @ W2.T + b2): M=32 K=96 N=48(keep 40) (waves 0-1) ----
    if (wv < 2) {
        floatx4 a2[3] = {};
        for (int kc = 0; kc < 3; ++kc) {
            short8 afz = *(const short8*)(const void*)
                &z1l[(wv * 16 + l15) * 104 + kc * 32 + quad * 8];
#pragma unroll
            for (int nt = 0; nt < 3; ++nt) {
                short8 bfr = *(const short8*)(const void*)
                    (W2bf + (size_t)(nt * 16 + l15) * 96 + kc * 32 + quad * 8);
                a2[nt] = __builtin_amdgcn_mfma_f32_16x16x32_bf16(afz, bfr, a2[nt], 0, 0, 0);
            }
        }
#pragma unroll
        for (int nt = 0; nt < 3; ++nt) {
            int n = nt * 16 + l15;
            if (n < 40) {
                float bb = b2[n];
#pragma unroll
                for (int rg = 0; rg < 4; ++rg)
                    z2l[(wv * 16 + quad * 4 + rg) * 44 + n] = fast_tanh(a2[nt][rg] + bb);
            }
        }
    }
    __syncthreads();

    // ---- final: out = sigmoid([z2, other] . W3 + b3) ----
    if (tid < 32) {
        float s = u[400] + ot[tid] + ot[32 + tid];
        for (int j = 0; j < 40; ++j) s = fmaf(z2l[tid * 44 + j], W3[j], s);
        out[b0 + tid] = fast_sigmoid(s);
    }
}

extern "C" void kernel_launch(void* const* d_in, const int* in_sizes, int n_in,
                              void* d_out, int out_size, void* d_ws, size_t ws_size,
                              hipStream_t stream)
{
    const float* x = (const float*)d_in[0];
    LW w;
    for (int i = 0; i < 16; ++i) w.p[i] = (const float*)d_in[1 + i];
    const float* Wp = (const float*)d_in[17];
    const float* bp = (const float*)d_in[18];
    const float* WH = (const float*)d_in[19];
    const float* bH = (const float*)d_in[20];
    const float* WL = (const float*)d_in[21];
    const float* bL = (const float*)d_in[22];
    const float* W1 = (const float*)d_in[23];
    const float* b1 = (const float*)d_in[24];
    const float* W2 = (const float*)d_in[25];
    const float* b2 = (const float*)d_in[26];
    const float* W3 = (const float*)d_in[27];
    const float* b3 = (const float*)d_in[28];

    char* ws = (char*)d_ws;
    __hip_bfloat16* hh   = (__hip_bfloat16*)(ws + WS_HH);
    __hip_bfloat16* WHbf = (__hip_bfloat16*)(ws + WS_WHB);
    __hip_bfloat16* WLbf = (__hip_bfloat16*)(ws + WS_WLB);
    __hip_bfloat16* W1bf = (__hip_bfloat16*)(ws + WS_W1B);
    __hip_bfloat16* W2bf = (__hip_bfloat16*)(ws + WS_W2B);
    float* u = (float*)(ws + WS_U);
    float* out = (float*)d_out;

    k_prep<<<400, 256, 0, stream>>>(WH, WL, W1, W2, W3, Wp, bp, b3,
                                    WHbf, WLbf, W1bf, W2bf, u);
    k_fused<<<1024, 256, 0, stream>>>(x, w, u, hh, WHbf, WLbf, bH, bL,
                                      W1bf, W2bf, b1, b2, W3, out);
}

// Round 6
// 308.237 us; speedup vs baseline: 1.0959x; 1.0317x over previous
//
#include <hip/hip_runtime.h>
#include <hip/hip_bf16.h>

#define BATCH 32768
#define TSEQ 200

typedef __attribute__((ext_vector_type(8))) short short8;
typedef __attribute__((ext_vector_type(4))) float floatx4;
typedef __attribute__((ext_vector_type(2))) float f32x2;

#if __has_builtin(__builtin_amdgcn_exp2f)
__device__ __forceinline__ float EXP2(float x) { return __builtin_amdgcn_exp2f(x); }
#else
__device__ __forceinline__ float EXP2(float x) {
    float r; asm("v_exp_f32 %0, %1" : "=v"(r) : "v"(x)); return r;
}
#endif
__device__ __forceinline__ float RCP(float x) { return __builtin_amdgcn_rcpf(x); }

__device__ __forceinline__ float fast_sigmoid(float x) {
    return RCP(1.0f + EXP2(-1.4426950408889634f * x));
}
__device__ __forceinline__ float fast_tanh(float x) {
    float e = EXP2(2.8853900817779268f * x);
    return 1.0f - 2.0f * RCP(e + 1.0f);
}
__device__ __forceinline__ short f2bfs(float v) {
    __hip_bfloat16 h = __float2bfloat16(v);
    return __builtin_bit_cast(short, h);
}
__device__ __forceinline__ f32x2 splat2(float x) { f32x2 v; v[0] = x; v[1] = x; return v; }
__device__ __forceinline__ f32x2 pkfma(f32x2 a, f32x2 b, f32x2 c) {
    return __builtin_elementwise_fma(a, b, c);
}
template <int K>
__device__ __forceinline__ float qb(float v) {
    int i = __builtin_bit_cast(int, v);
    int r = __builtin_amdgcn_update_dpp(i, i, K * 0x55, 0xf, 0xf, false);
    return __builtin_bit_cast(float, r);
}
__device__ __forceinline__ void async16(void* lds, const void* g) {
    __builtin_amdgcn_global_load_lds(
        (const __attribute__((address_space(1))) unsigned int*)g,
        (__attribute__((address_space(3))) unsigned int*)lds, 16, 0, 0);
}

#define S_SIG (-1.4426950408889634f)   // sigmoid rows: 2^(S_SIG*g) = e^-g
#define S_TANH (2.8853900817779268f)   // tanh rows:    2^(S_TANH*g) = e^(2g)

// ---------------- workspace layout (bytes) ----------------
// hh k-index: k' = (t>>2)*16 + q*4 + (t&3)  — quad-contiguous 32B stores
#define WS_HH  0                         // bf16 [2][B][800]
#define WS_WHB 104857600                 // bf16 [128][800] cols permuted to k'
#define WS_WLB (WS_WHB + 204800)
#define WS_W1B (WS_WLB + 204800)         // bf16 [80][256]
#define WS_W2B (WS_W1B + 40960)          // bf16 [48][96] zero-pad
#define WS_U   (WS_W2B + 9216)           // f32 [401]

struct LW { const float* p[16]; };

// ---------------- kernel 0: weight prep / folds ----------------
__global__ __launch_bounds__(256) void k_prep(
    const float* __restrict__ WH, const float* __restrict__ WL,
    const float* __restrict__ W1, const float* __restrict__ W2,
    const float* __restrict__ W3, const float* __restrict__ Wp,
    const float* __restrict__ bp, const float* __restrict__ b3,
    __hip_bfloat16* __restrict__ WHbf, __hip_bfloat16* __restrict__ WLbf,
    __hip_bfloat16* __restrict__ W1bf, __hip_bfloat16* __restrict__ W2bf,
    float* __restrict__ u)
{
    int gid = blockIdx.x * 256 + threadIdx.x;   // 400 blocks = 102400 = 128*800
    int n = gid / 800, k = gid - n * 800;
    int t = k >> 2, q = k & 3;
    int kp = (t >> 2) * 16 + q * 4 + (t & 3);
    int dst = n * 800 + kp;
    WHbf[dst] = __float2bfloat16(WH[gid]);
    WLbf[dst] = __float2bfloat16(WL[gid]);
    if (gid < 20480) W1bf[gid] = __float2bfloat16(W1[gid]);
    if (gid < 4608) {
        int rr = gid / 96, cc = gid - rr * 96;
        float v = (rr < 40 && cc < 80) ? W2[rr * 80 + cc] : 0.0f;
        W2bf[gid] = __float2bfloat16(v);
    }
    if (gid < 400) {
        float a = 0.f;
        for (int j = 0; j < 40; ++j) a = fmaf(W3[40 + j], Wp[j * 400 + gid], a);
        u[gid] = a;
    } else if (gid == 400) {
        float a = b3[0];
        for (int j = 0; j < 40; ++j) a = fmaf(W3[40 + j], bp[j], a);
        u[400] = a;
    }
}

// One skewed round: computes layer-1 for step t-1 (from h0[t-1], h1[t-2])
// and layer-0 for step t (from x[t], h0[t-1]). The two halves are mutually
// independent -> scheduler interleaves two ~45-instr chains (ILP x2).
// M: 0 = both, 1 = L0 only (peel r=0), 2 = L1 only (tail r=200).
// Bit-exact vs the sequential version: per-gate fma order is unchanged, and
// L1's h0-broadcasts equal L0's a-broadcasts (same carried value).
template <int M>
__device__ __forceinline__ float lstm_round(
    float xt, float& h0, float& c0, float& h1, float& c1,
    const f32x2 (&wx0p)[2], const f32x2 (&bb0p)[2], const f32x2 (&whh0p)[2][4],
    const f32x2 (&bb1p)[2], const f32x2 (&wih1p)[2][4], const f32x2 (&whh1p)[2][4])
{
    float a0 = qb<0>(h0), a1 = qb<1>(h0), a2 = qb<2>(h0), a3 = qb<3>(h0);
    float h1out = 0.f;

    if (M != 1) {   // ---- layer 1, step t-1 ----
        float q0 = qb<0>(h1), q1 = qb<1>(h1), q2 = qb<2>(h1), q3 = qb<3>(h1);
        f32x2 G0 = bb1p[0], G1 = bb1p[1];
        G0 = pkfma(wih1p[0][0], splat2(a0), G0); G1 = pkfma(wih1p[1][0], splat2(a0), G1);
        G0 = pkfma(wih1p[0][1], splat2(a1), G0); G1 = pkfma(wih1p[1][1], splat2(a1), G1);
        G0 = pkfma(wih1p[0][2], splat2(a2), G0); G1 = pkfma(wih1p[1][2], splat2(a2), G1);
        G0 = pkfma(wih1p[0][3], splat2(a3), G0); G1 = pkfma(wih1p[1][3], splat2(a3), G1);
        G0 = pkfma(whh1p[0][0], splat2(q0), G0); G1 = pkfma(whh1p[1][0], splat2(q0), G1);
        G0 = pkfma(whh1p[0][1], splat2(q1), G0); G1 = pkfma(whh1p[1][1], splat2(q1), G1);
        G0 = pkfma(whh1p[0][2], splat2(q2), G0); G1 = pkfma(whh1p[1][2], splat2(q2), G1);
        G0 = pkfma(whh1p[0][3], splat2(q3), G0); G1 = pkfma(whh1p[1][3], splat2(q3), G1);
        float ig = RCP(1.0f + EXP2(G0[0]));
        float fg = RCP(1.0f + EXP2(G0[1]));
        float og = RCP(1.0f + EXP2(G1[1]));
        float tg = 1.0f - 2.0f * RCP(EXP2(G1[0]) + 1.0f);
        c1 = fmaf(fg, c1, ig * tg);
        float th1 = 1.0f - 2.0f * RCP(EXP2(S_TANH * c1) + 1.0f);
        h1 = og * th1;
        h1out = h1;
    }

    if (M != 2) {   // ---- layer 0, step t ----
        f32x2 g0 = pkfma(splat2(xt), wx0p[0], bb0p[0]);
        f32x2 g1 = pkfma(splat2(xt), wx0p[1], bb0p[1]);
        g0 = pkfma(whh0p[0][0], splat2(a0), g0); g1 = pkfma(whh0p[1][0], splat2(a0), g1);
        g0 = pkfma(whh0p[0][1], splat2(a1), g0); g1 = pkfma(whh0p[1][1], splat2(a1), g1);
        g0 = pkfma(whh0p[0][2], splat2(a2), g0); g1 = pkfma(whh0p[1][2], splat2(a2), g1);
        g0 = pkfma(whh0p[0][3], splat2(a3), g0); g1 = pkfma(whh0p[1][3], splat2(a3), g1);
        float ig = RCP(1.0f + EXP2(g0[0]));
        float fg = RCP(1.0f + EXP2(g0[1]));
        float og = RCP(1.0f + EXP2(g1[1]));
        float tg = 1.0f - 2.0f * RCP(EXP2(g1[0]) + 1.0f);
        c0 = fmaf(fg, c0, ig * tg);
        float th0 = 1.0f - 2.0f * RCP(EXP2(S_TANH * c0) + 1.0f);
        h0 = og * th0;
    }
    return h1out;
}

// ---------------- kernel 1: fused LSTM + GEMM + MLP tail ----------------
__global__ __launch_bounds__(256)
__attribute__((amdgpu_waves_per_eu(4, 4))) void k_fused(
    const float* __restrict__ x, LW w, const float* __restrict__ u,
    __hip_bfloat16* __restrict__ hh,
    const __hip_bfloat16* __restrict__ WHbf, const __hip_bfloat16* __restrict__ WLbf,
    const float* __restrict__ bH, const float* __restrict__ bL,
    const __hip_bfloat16* __restrict__ W1bf, const __hip_bfloat16* __restrict__ W2bf,
    const float* __restrict__ b1, const float* __restrict__ b2,
    const float* __restrict__ W3, float* __restrict__ out)
{
    // 0..32767:  Bs [2][256][32] bf16 staging; aliased after GEMM by:
    //   zl  [32][264] bf16 @ 0      (16896 B)
    //   z1l [32][104] bf16 @ 17024  (6656 B)
    //   z2l [32][44]  f32  @ 23808  (5632 B)
    // 32768..33023: ot [64] f32
    __shared__ __align__(16) char smem[33024];
    short* Bse = (short*)smem;
    short* zl  = (short*)smem;
    short* z1l = (short*)(smem + 17024);
    float* z2l = (float*)(smem + 23808);
    float* ot  = (float*)(smem + 32768);

    int tid = threadIdx.x;
    int q = tid & 3;
    int g = tid >> 2;                    // 0..63: group in block
    int r = tid >> 7;                    // wave-uniform rnn index
    int b = blockIdx.x * 32 + (g & 31);

    const float* Wih0 = w.p[r * 8 + 0];
    const float* Whh0 = w.p[r * 8 + 1];
    const float* bih0 = w.p[r * 8 + 2];
    const float* bhh0 = w.p[r * 8 + 3];
    const float* Wih1 = w.p[r * 8 + 4];
    const float* Whh1 = w.p[r * 8 + 5];
    const float* bih1 = w.p[r * 8 + 6];
    const float* bhh1 = w.p[r * 8 + 7];

    // pairs: p=0 -> (i,f) [sigmoid], p=1 -> (g,o) [tanh, sigmoid]
    f32x2 wx0p[2], bb0p[2], bb1p[2], whh0p[2][4], wih1p[2][4], whh1p[2][4];
#pragma unroll
    for (int p = 0; p < 2; ++p) {
#pragma unroll
        for (int c = 0; c < 2; ++c) {
            int G = 2 * p + c;
            int j = 4 * G + q;
            float sc = (G == 2) ? S_TANH : S_SIG;
            wx0p[p][c] = Wih0[j] * sc;
            bb0p[p][c] = (bih0[j] + bhh0[j]) * sc;
            bb1p[p][c] = (bih1[j] + bhh1[j]) * sc;
#pragma unroll
            for (int k = 0; k < 4; ++k) {
                whh0p[p][k][c] = Whh0[j * 4 + k] * sc;
                wih1p[p][k][c] = Wih1[j * 4 + k] * sc;
                whh1p[p][k][c] = Whh1[j * 4 + k] * sc;
            }
        }
    }

    const float* xp = x + ((size_t)b * 2 + r) * TSEQ;
    const float* up = u + r * TSEQ;
    __hip_bfloat16* hp = hh + ((size_t)r * BATCH + b) * 800 + q * 4;

    float h0 = 0.f, c0 = 0.f, h1 = 0.f, c1 = 0.f, accO = 0.f;

    float4 xv_prev = *(const float4*)xp;     // x[0..3]
    float4 uv_prev = *(const float4*)up;

    // peel round 0: layer-0 only
    accO = fmaf(xv_prev.x, uv_prev.x, accO);
    lstm_round<1>(xv_prev.x, h0, c0, h1, c1,
                  wx0p, bb0p, whh0p, bb1p, wih1p, whh1p);

    // main: blocks of 4 rounds; block tb covers rounds tb+1..tb+4,
    // producing h1 for t = tb..tb+3 (stored as before at hp + tb*4).
    for (int tb = 0; tb <= 192; tb += 4) {
        float4 xv_new = *(const float4*)(xp + tb + 4);
        float4 uv_new = *(const float4*)(up + tb + 4);
        float xc[4] = {xv_prev.y, xv_prev.z, xv_prev.w, xv_new.x};
        float uc[4] = {uv_prev.y, uv_prev.z, uv_prev.w, uv_new.x};
        float hb[4];
#pragma unroll
        for (int j = 0; j < 4; ++j) {
            accO = fmaf(xc[j], uc[j], accO);
            hb[j] = lstm_round<0>(xc[j], h0, c0, h1, c1,
                                  wx0p, bb0p, whh0p, bb1p, wih1p, whh1p);
        }
        ushort4 pk;
        pk.x = (unsigned short)f2bfs(hb[0]);
        pk.y = (unsigned short)f2bfs(hb[1]);
        pk.z = (unsigned short)f2bfs(hb[2]);
        pk.w = (unsigned short)f2bfs(hb[3]);
        *(ushort4*)(hp + tb * 4) = pk;   // quad-contiguous 32B stores
        xv_prev = xv_new; uv_prev = uv_new;
    }

    // tail: rounds 197..199 (both layers) + round 200 (layer-1 only)
    {
        float xc[3] = {xv_prev.y, xv_prev.z, xv_prev.w};   // x[197..199]
        float uc[3] = {uv_prev.y, uv_prev.z, uv_prev.w};
        float hb[4];
#pragma unroll
        for (int j = 0; j < 3; ++j) {
            accO = fmaf(xc[j], uc[j], accO);
            hb[j] = lstm_round<0>(xc[j], h0, c0, h1, c1,
                                  wx0p, bb0p, whh0p, bb1p, wih1p, whh1p);
        }
        hb[3] = lstm_round<2>(0.f, h0, c0, h1, c1,
                              wx0p, bb0p, whh0p, bb1p, wih1p, whh1p);
        ushort4 pk;
        pk.x = (unsigned short)f2bfs(hb[0]);
        pk.y = (unsigned short)f2bfs(hb[1]);
        pk.z = (unsigned short)f2bfs(hb[2]);
        pk.w = (unsigned short)f2bfs(hb[3]);
        *(ushort4*)(hp + 196 * 4) = pk;
    }
    if (q == 0) ot[g] = accO;
    __syncthreads();   // drains hh stores + ot visible

    // ---- epilogue: z = tanh(hh @ W.T + b) for this block's 32 samples ----
    int wv = tid >> 6, lane = tid & 63, l15 = lane & 15, quad = lane >> 4;
    int b0 = blockIdx.x * 32;
    int f = wv >> 1, mt = wv & 1;        // wave -> (gemm half, 16-row tile)

    // B staging, TRANSPOSED chunks: each 1KB chunk = 16-row x 64B W-tile;
    // lane l fetches global row (l&15), 16B-col (l>>4), so the MFMA B-read
    // is identity lane->lane*16B: consecutive banks, 0 conflicts (R3: 37x
    // conflict drop, verified).
    const __hip_bfloat16* gB0 = WHbf + (size_t)(wv * 16 + (tid & 15)) * 800 + ((tid >> 4) & 3) * 8;
    const __hip_bfloat16* gB2 = WLbf + (size_t)(wv * 16 + (tid & 15)) * 800 + ((tid >> 4) & 3) * 8;
    // each wave reads back the hh rows its own lanes produced (L2-warm)
    const __hip_bfloat16* Ab =
        hh + ((size_t)f * BATCH + b0 + mt * 16 + l15) * 800 + quad * 8;

#define PF(kc, buf)                                                    \
    do {                                                               \
        char* lb_ = smem + (buf) * 16384 + wv * 1024;                  \
        async16(lb_,          gB0 + (kc) * 32);                        \
        async16(lb_ + 4096,   gB0 + 64 * 800 + (kc) * 32);             \
        async16(lb_ + 8192,   gB2 + (kc) * 32);                        \
        async16(lb_ + 12288,  gB2 + 64 * 800 + (kc) * 32);             \
    } while (0)

    floatx4 acc[8] = {};
    short8 af = *(const short8*)(const void*)Ab;
    PF(0, 0);
    for (int kc = 0; kc < 25; ++kc) {
        __syncthreads();
        short8 afn = af;
        if (kc < 24) {
            PF(kc + 1, (kc + 1) & 1);
            afn = *(const short8*)(const void*)(Ab + (kc + 1) * 32);
        }
        // chunk nt of [WH;WL] half f, identity slot = lane
        const short* Bb = Bse + (kc & 1) * 8192 + f * 4096 + lane * 8;
#pragma unroll
        for (int nt = 0; nt < 8; ++nt) {
            short8 bfr = *(const short8*)(const void*)(Bb + nt * 512);
            acc[nt] = __builtin_amdgcn_mfma_f32_16x16x32_bf16(af, bfr, acc[nt], 0, 0, 0);
        }
        af = afn;
    }
#undef PF
    __syncthreads();   // Bs dead from here; write z into aliased region

    {
        const float* bias = f ? bL : bH;
#pragma unroll
        for (int nt = 0; nt < 8; ++nt) {
            float bb = bias[nt * 16 + l15];
            int c = f * 128 + nt * 16 + l15;
#pragma unroll
            for (int rg = 0; rg < 4; ++rg) {
                int m = mt * 16 + quad * 4 + rg;
                zl[m * 264 + c] = f2bfs(fast_tanh(acc[nt][rg] + bb));
            }
        }
    }
    __syncthreads();

    // ---- z1 = tanh(z @ W1.T + b1): M=32 K=256 N=80 (waves 0-1) ----
    if (wv < 2) {
        floatx4 a1[5] = {};
        for (int kc = 0; kc < 8; ++kc) {
            short8 afz = *(const short8*)(const void*)
                &zl[(wv * 16 + l15) * 264 + kc * 32 + quad * 8];
#pragma unroll
            for (int nt = 0; nt < 5; ++nt) {
                short8 bfr = *(const short8*)(const void*)
                    (W1bf + (size_t)(nt * 16 + l15) * 256 + kc * 32 + quad * 8);
                a1[nt] = __builtin_amdgcn_mfma_f32_16x16x32_bf16(afz, bfr, a1[nt], 0, 0, 0);
            }
        }
#pragma unroll
        for (int nt = 0; nt < 5; ++nt) {
            int n = nt * 16 + l15;
            float bb = b1[n];
#pragma unroll
            for (int rg = 0; rg < 4; ++rg)
                z1l[(wv * 16 + quad * 4 + rg) * 104 + n] = f2bfs(fast_tanh(a1[nt][rg] + bb));
        }
    } else {
        // zero-pad z1 cols 80..95 (K-pad for z2's 96-wide contraction)
        int i0 = tid - 128;
        for (int i = i0; i < 512; i += 128) {
            int rr = i >> 4, cc = 80 + (i & 15);
            z1l[rr * 104 + cc] = 0;
        }
    }
    __syncthreads();

    // ---- z2 = tanh(z1 @ W2.T + b2): M=32 K=96 N=48(keep 40) (waves 0-1) ----
    if (wv < 2) {
        floatx4 a2[3] = {};
        for (int kc = 0; kc < 3; ++kc) {
            short8 afz = *(const short8*)(const void*)
                &z1l[(wv * 16 + l15) * 104 + kc * 32 + quad * 8];
#pragma unroll
            for (int nt = 0; nt < 3; ++nt) {
                short8 bfr = *(const short8*)(const void*)
                    (W2bf + (size_t)(nt * 16 + l15) * 96 + kc * 32 + quad * 8);
                a2[nt] = __builtin_amdgcn_mfma_f32_16x16x32_bf16(afz, bfr, a2[nt], 0, 0, 0);
            }
        }
#pragma unroll
        for (int nt = 0; nt < 3; ++nt) {
            int n = nt * 16 + l15;
            if (n < 40) {
                float bb = b2[n];
#pragma unroll
                for (int rg = 0; rg < 4; ++rg)
                    z2l[(wv * 16 + quad * 4 + rg) * 44 + n] = fast_tanh(a2[nt][rg] + bb);
            }
        }
    }
    __syncthreads();

    // ---- final: out = sigmoid([z2, other] . W3 + b3) ----
    if (tid < 32) {
        float s = u[400] + ot[tid] + ot[32 + tid];
        for (int j = 0; j < 40; ++j) s = fmaf(z2l[tid * 44 + j], W3[j], s);
        out[b0 + tid] = fast_sigmoid(s);
    }
}

extern "C" void kernel_launch(void* const* d_in, const int* in_sizes, int n_in,
                              void* d_out, int out_size, void* d_ws, size_t ws_size,
                              hipStream_t stream)
{
    const float* x = (const float*)d_in[0];
    LW w;
    for (int i = 0; i < 16; ++i) w.p[i] = (const float*)d_in[1 + i];
    const float* Wp = (const float*)d_in[17];
    const float* bp = (const float*)d_in[18];
    const float* WH = (const float*)d_in[19];
    const float* bH = (const float*)d_in[20];
    const float* WL = (const float*)d_in[21];
    const float* bL = (const float*)d_in[22];
    const float* W1 = (const float*)d_in[23];
    const float* b1 = (const float*)d_in[24];
    const float* W2 = (const float*)d_in[25];
    const float* b2 = (const float*)d_in[26];
    const float* W3 = (const float*)d_in[27];
    const float* b3 = (const float*)d_in[28];

    char* ws = (char*)d_ws;
    __hip_bfloat16* hh   = (__hip_bfloat16*)(ws + WS_HH);
    __hip_bfloat16* WHbf = (__hip_bfloat16*)(ws + WS_WHB);
    __hip_bfloat16* WLbf = (__hip_bfloat16*)(ws + WS_WLB);
    __hip_bfloat16* W1bf = (__hip_bfloat16*)(ws + WS_W1B);
    __hip_bfloat16* W2bf = (__hip_bfloat16*)(ws + WS_W2B);
    float* u = (float*)(ws + WS_U);
    float* out = (float*)d_out;

    k_prep<<<400, 256, 0, stream>>>(WH, WL, W1, W2, W3, Wp, bp, b3,
                                    WHbf, WLbf, W1bf, W2bf, u);
    k_fused<<<1024, 256, 0, stream>>>(x, w, u, hh, WHbf, WLbf, bH, bL,
                                      W1bf, W2bf, b1, b2, W3, out);
}